// Round 3
// baseline (312.160 us; speedup 1.0000x reference)
//
#include <hip/hip_runtime.h>
#include <hip/hip_bf16.h>

#define IN_D 16
#define ROW_F 273                    // floats per output row (1 + 16 + 256)
#define GROUP_ROWS 4
#define GROUP_V4 273                 // float4 per 4-row group (1092 floats, 16B-aligned)

// One wave per 4-row group (4 rows x 273 = 1092 floats = 273 float4).
// Wave stages its 64 input floats in a private 256B LDS slice (intra-wave
// only -> no barriers), then emits 273 aligned float4 stores; each output
// scalar fetches its operands by direct LDS read (broadcast-heavy -> no
// bank conflicts). All register indexing is compile-time (rule #20).
__global__ __launch_bounds__(256) void TaylorExp_kernel(
    const float* __restrict__ x, float4* __restrict__ out, int ngroups) {
    __shared__ float X[4][64];      // per-wave 64-float slice
    const int lane = threadIdx.x & 63;
    const int w = threadIdx.x >> 6;
    const int wid = blockIdx.x * 4 + w;
    const int wstride = gridDim.x * 4;

    const float QS = 0.17677669529663689f;  // 1/(sqrt(2)*sqrt(16))
    float* Xw = &X[w][0];

    for (int g = wid; g < ngroups; g += wstride) {
        // coalesced 256B load: lane l holds x[4g + l/16][l%16]
        float v = x[(size_t)g * 64 + lane];
        Xw[lane] = v;   // wave-synchronous; compiler inserts lgkmcnt waits

        float4* obase = out + (size_t)g * GROUP_V4;

        #pragma unroll
        for (int it = 0; it < 5; ++it) {
            int m = it * 64 + lane;                   // float4 index in group
            bool act = m < GROUP_V4;
            int mm = act ? m : GROUP_V4 - 1;
            float4 o;
            float* op = &o.x;
            #pragma unroll
            for (int k = 0; k < 4; ++k) {
                int f = mm * 4 + k;                   // flat float index in group
                // r = f / 273 via compare tree (f < 1092)
                int r = (f >= 2 * ROW_F) ? ((f >= 3 * ROW_F) ? 3 : 2)
                                         : ((f >= ROW_F) ? 1 : 0);
                int c = f - r * ROW_F;
                int q = c - 17;
                bool quad = (q >= 0);
                int ia = quad ? (q >> 4) : (c > 0 ? c - 1 : 0);
                int ib = quad ? (q & 15) : ia;
                float a = Xw[r * 16 + ia];
                float b = Xw[r * 16 + ib];
                float val = quad ? (a * b * QS)
                                 : ((c == 0) ? 1.0f : a * 0.5f);
                op[k] = val;
            }
            if (act) obase[m] = o;
        }
    }
}

extern "C" void kernel_launch(void* const* d_in, const int* in_sizes, int n_in,
                              void* d_out, int out_size, void* d_ws, size_t ws_size,
                              hipStream_t stream) {
    const float* x = (const float*)d_in[0];
    float4* out = (float4*)d_out;
    const int nrows = in_sizes[0] / IN_D;    // 262144
    const int ngroups = nrows / GROUP_ROWS;  // 65536

    const int block = 256;                   // 4 waves/block
    const int waves_per_block = block / 64;
    int blocks_needed = (ngroups + waves_per_block - 1) / waves_per_block;
    int grid = blocks_needed < 2048 ? blocks_needed : 2048;  // grid-stride the rest

    TaylorExp_kernel<<<grid, block, 0, stream>>>(x, out, ngroups);
}